// Round 5
// baseline (429.246 us; speedup 1.0000x reference)
//
#include <hip/hip_runtime.h>
#include <hip/hip_bf16.h>
#include <math.h>

#define N 320
#define NN (N * N)          // 102400
#define SST 324             // LDS fp32 row stride for S scratch

typedef float f32x16 __attribute__((ext_vector_type(16)));
typedef short s16x8  __attribute__((ext_vector_type(8)));

#define MFMA32(a, b, c) __builtin_amdgcn_mfma_f32_32x32x16_bf16((a), (b), (c), 0, 0, 0)

union U4V { uint4 q; s16x8 v; };

// truncation split: x = hi + lo with hi,lo bf16 (round-toward-zero; rel err ~2^-16 combined)
__device__ inline void split2(float x0, float x1, unsigned& hi, unsigned& lo) {
    unsigned u0 = __float_as_uint(x0), u1 = __float_as_uint(x1);
    hi = (u0 >> 16) | (u1 & 0xFFFF0000u);
    float d0 = x0 - __uint_as_float(u0 & 0xFFFF0000u);
    float d1 = x1 - __uint_as_float(u1 & 0xFFFF0000u);
    lo = (__float_as_uint(d0) >> 16) | (__float_as_uint(d1) & 0xFFFF0000u);
}

// ---------------- fused prep ----------------
// block roles:
//   [  0,100) zero wbuf
//   [100,200) zero out
//   [200,202) colsum[e] = sum_t s[t][e]
//   [202,252) pack s^T   (4 sub-blocks of 64 lanes per block)
//   [252,302) pack W^T
__global__ __launch_bounds__(256) void prep_kernel(
    const float* __restrict__ s, const float* __restrict__ W,
    float* __restrict__ wbuf, float* __restrict__ out, float* __restrict__ colsum,
    uint4* __restrict__ spH, uint4* __restrict__ spL,
    uint4* __restrict__ wpH, uint4* __restrict__ wpL)
{
    const int bid = blockIdx.x;
    const int tid = threadIdx.x;
    if (bid < 100) {
        ((float4*)wbuf)[bid * 256 + tid] = make_float4(0.f, 0.f, 0.f, 0.f);
    } else if (bid < 200) {
        ((float4*)out)[(bid - 100) * 256 + tid] = make_float4(0.f, 0.f, 0.f, 0.f);
    } else if (bid < 202) {
        int e = (bid - 200) * 256 + tid;
        if (e < N) {
            const float* sp = s + e;
            float a[8];
#pragma unroll
            for (int u = 0; u < 8; ++u) a[u] = 0.f;
            for (int t = 0; t < N; t += 8) {
#pragma unroll
                for (int u = 0; u < 8; ++u) a[u] += sp[(size_t)(t + u) * N];
            }
            colsum[e] = ((a[0] + a[1]) + (a[2] + a[3])) + ((a[4] + a[5]) + (a[6] + a[7]));
        }
    } else if (bid < 252) {
        int sub = (bid - 202) * 4 + (tid >> 6);     // 0..199 = et*20 + ts
        int l = tid & 63;
        int et = sub / 20, ts = sub % 20;
        int e = et * 32 + (l & 31);
        int t0 = ts * 16 + (l >> 5) * 8;
        unsigned hi[4], lo[4];
#pragma unroll
        for (int d = 0; d < 4; ++d)
            split2(s[(size_t)(t0 + 2 * d) * N + e], s[(size_t)(t0 + 2 * d + 1) * N + e],
                   hi[d], lo[d]);
        spH[sub * 64 + l] = make_uint4(hi[0], hi[1], hi[2], hi[3]);
        spL[sub * 64 + l] = make_uint4(lo[0], lo[1], lo[2], lo[3]);
    } else {
        int sub = (bid - 252) * 4 + (tid >> 6);     // 0..199 = jt*20 + ks
        int l = tid & 63;
        int jt = sub / 20, ks = sub % 20;
        int j = jt * 32 + (l & 31);
        int k0 = ks * 16 + (l >> 5) * 8;
        const float* wr = W + (size_t)j * N + k0;
        unsigned hi[4], lo[4];
#pragma unroll
        for (int d = 0; d < 4; ++d) split2(wr[2 * d], wr[2 * d + 1], hi[d], lo[d]);
        wpH[sub * 64 + l] = make_uint4(hi[0], hi[1], hi[2], hi[3]);
        wpL[sub * 64 + l] = make_uint4(lo[0], lo[1], lo[2], lo[3]);
    }
}

// ---------------- packf: F -> bf16 hi/lo MFMA B-fragments, coalesced via LDS ----------
// block = (i, ts-quad): 1600 blocks x 320 threads. Per ts: stage 16x320 f32 tile
// with float4 coalesced loads, LDS-transpose to (j per lane, k in regs), split2,
// store coalesced uint4 fragments. LDS reads: addr (k*320+j), bank = j%32 ->
// lanes hold distinct j within a 32-group -> conflict-free (hf pair is 2-way = free).
__global__ __launch_bounds__(320) void packf_kernel(
    const float* __restrict__ fut,
    uint4* __restrict__ fpH, uint4* __restrict__ fpL)
{
    const int bid = blockIdx.x;        // i*5 + tq
    const int i = bid / 5, tq = bid % 5;
    const int t = threadIdx.x;
    const int l = t & 63, l31 = l & 31, hf = l >> 5;
    const int jt0 = t >> 6;            // 0..4

    __shared__ float ld[16 * 320];     // 20480 B

    for (int tt = 0; tt < 4; ++tt) {
        const int ts = tq * 4 + tt;
        const float4* src = (const float4*)(fut + (size_t)i * NN + (size_t)ts * 16 * N);
        if (tt) __syncthreads();       // previous pack-reads done before overwrite
#pragma unroll
        for (int rep = 0; rep < 4; ++rep)
            ((float4*)ld)[rep * 320 + t] = src[rep * 320 + t];
        __syncthreads();
#pragma unroll
        for (int rr = 0; rr < 2; ++rr) {
            const int jt = jt0 + rr * 5;
            const int j = jt * 32 + l31;
            unsigned hi[4], lo[4];
#pragma unroll
            for (int d = 0; d < 4; ++d) {
                float x0 = ld[(hf * 8 + 2 * d) * 320 + j];
                float x1 = ld[(hf * 8 + 2 * d + 1) * 320 + j];
                split2(x0, x1, hi[d], lo[d]);
            }
            size_t sub = (size_t)(i * 10 + jt) * 20 + ts;
            fpH[sub * 64 + l] = make_uint4(hi[0], hi[1], hi[2], hi[3]);
            fpL[sub * 64 + l] = make_uint4(lo[0], lo[1], lo[2], lo[3]);
        }
    }
}

// ---------------- fused: per (i, e-slab 32), 3200 blocks ----------------
// XCD swizzle: i = (bid/80)*8 + (bid&7) so consecutive bids on one XCD share i
// (F_i fragments L2-hot). Inner loop: 4 uint4 loads + 3 MFMAs in TWO accumulator
// chains (acc1 = ah*bh; acc2 = al*bh + ah*bl) -> ~80 total regs (2.4 blocks/CU)
// vs round-2's 3-chain 112 regs (1.6 blocks/CU).
__global__ __launch_bounds__(640, 5) void fused_kernel(
    const uint4* __restrict__ fpH, const uint4* __restrict__ fpL,
    const uint4* __restrict__ spH, const uint4* __restrict__ spL,
    const uint4* __restrict__ wpH, const uint4* __restrict__ wpL,
    const float* __restrict__ bvec, const float* __restrict__ colsum,
    float* __restrict__ w)
{
    const int bid = blockIdx.x;
    const int i   = (bid / 80) * 8 + (bid & 7);
    const int et  = (bid >> 3) % 10;
    const int tid = threadIdx.x;
    const int wid = tid >> 6;         // wave 0..9 = 32-wide column tile
    const int lane = tid & 63;
    const int l31 = lane & 31;
    const int hf  = lane >> 5;

    // G in LDS: frag-linear, XOR-swizzled 16B chunks (proven layout, 0 conflicts).
    __shared__ union {
        unsigned short G[2][40 * 32 * 8];   // [hi/lo] 20KB each
        float S[32 * SST];                  // softmax scratch
    } sm;
    __shared__ float csh[32];
    __shared__ float Mfin[32];
    __shared__ float Ifin[32];

    if (tid < 32) csh[tid] = colsum[et * 32 + tid];

    // ---------------- phase A: G = s^T @ F_i (column tile wid) ----------------
    f32x16 acc1, acc2;
#pragma unroll
    for (int r = 0; r < 16; ++r) { acc1[r] = 0.f; acc2[r] = 0.f; }

    const uint4* fH  = fpH + (size_t)((i * 10 + wid) * 20) * 64 + lane;
    const uint4* fL  = fpL + (size_t)((i * 10 + wid) * 20) * 64 + lane;
    const uint4* aHp = spH + (size_t)(et * 20) * 64 + lane;
    const uint4* aLp = spL + (size_t)(et * 20) * 64 + lane;

#pragma unroll 2
    for (int ts = 0; ts < 20; ++ts) {
        U4V ah, al, bh, bl;
        ah.q = aHp[ts * 64];
        al.q = aLp[ts * 64];
        bh.q = fH[ts * 64];
        bl.q = fL[ts * 64];
        acc1 = MFMA32(ah.v, bh.v, acc1);
        acc2 = MFMA32(al.v, bh.v, acc2);
        acc2 = MFMA32(ah.v, bl.v, acc2);
    }

    // G -> LDS bf16 hi/lo in frag-linear swizzled layout
    {
        const int c  = wid * 4 + (l31 >> 3);
        const int jj = l31 & 7;
        const int sw = c & 7;
        unsigned short* GH = sm.G[0];
        unsigned short* GL = sm.G[1];
#pragma unroll
        for (int r = 0; r < 16; ++r) {
            int e = (r & 3) + ((r >> 2) << 3) + (hf << 2);
            float x = acc1[r] + acc2[r];
            unsigned u = __float_as_uint(x);
            float d = x - __uint_as_float(u & 0xFFFF0000u);
            int off = (c * 32 + (e ^ sw)) * 8 + jj;
            GH[off] = (unsigned short)(u >> 16);
            GL[off] = (unsigned short)(__float_as_uint(d) >> 16);
        }
    }
    __syncthreads();   // B1: G + csh visible

    // ---------------- phase B: S = G @ W^T (+ colsum*b) ----------------
    f32x16 p1, p2;
#pragma unroll
    for (int r = 0; r < 16; ++r) { p1[r] = 0.f; p2[r] = 0.f; }

    const uint4* bHp = wpH + (size_t)(wid * 20) * 64 + lane;
    const uint4* bLp = wpL + (size_t)(wid * 20) * 64 + lane;
    const unsigned short* GH = sm.G[0];
    const unsigned short* GL = sm.G[1];

#pragma unroll 4
    for (int ks = 0; ks < 20; ++ks) {
        int c = ks * 2 + hf;
        int off = (c * 32 + (l31 ^ (c & 7))) * 8;
        s16x8 gh = *(const s16x8*)&GH[off];
        s16x8 gl = *(const s16x8*)&GL[off];
        U4V wh, wl;
        wh.q = bHp[ks * 64];
        wl.q = bLp[ks * 64];
        p1 = MFMA32(gh, wh.v, p1);
        p2 = MFMA32(gl, wh.v, p2);
        p2 = MFMA32(gh, wl.v, p2);
    }

    const int jcol = wid * 32 + l31;
    float bj = bvec[jcol];
    float v[16];
#pragma unroll
    for (int r = 0; r < 16; ++r) {
        int e = (r & 3) + ((r >> 2) << 3) + (hf << 2);
        v[r] = (p1[r] + p2[r]) + csh[e] * bj;
    }

    __syncthreads();   // B2: all waves done reading G before S overwrites union

#pragma unroll
    for (int r = 0; r < 16; ++r) {
        int e = (r & 3) + ((r >> 2) << 3) + (hf << 2);
        sm.S[e * SST + jcol] = v[r];
    }
    __syncthreads();   // B3

    // row sweeps: half-wave hw (0..15) handles rows 2hw, 2hw+1
    const int hw = tid >> 5;
    const int li = tid & 31;
    if (hw < 16) {
#pragma unroll
        for (int rr = 0; rr < 2; ++rr) {
            int row = 2 * hw + rr;
            float x[10];
            float m = -3.4e38f;
#pragma unroll
            for (int q = 0; q < 10; ++q) {
                x[q] = sm.S[row * SST + li + 32 * q];
                m = fmaxf(m, x[q]);
            }
#pragma unroll
            for (int off = 16; off; off >>= 1) m = fmaxf(m, __shfl_xor(m, off, 64));
            float ssum = 0.f;
#pragma unroll
            for (int q = 0; q < 10; ++q) ssum += __expf(x[q] - m);
#pragma unroll
            for (int off = 16; off; off >>= 1) ssum += __shfl_xor(ssum, off, 64);
            if (li == 0) { Mfin[row] = m; Ifin[row] = 1.0f / ssum; }
        }
    }
    __syncthreads();   // B4

    float wcol = 0.f;
#pragma unroll
    for (int r = 0; r < 16; ++r) {
        int e = (r & 3) + ((r >> 2) << 3) + (hf << 2);
        wcol += __expf(v[r] - Mfin[e]) * Ifin[e];
    }
    wcol += __shfl_xor(wcol, 32, 64);
    if (hf == 0) atomicAdd(&w[(size_t)i * N + jcol], wcol);
}

// ---------------- out[i][k] += sum_{j in chunk} w[i][j] * s[j][k] ----------------
__global__ __launch_bounds__(320) void out_gemm_kernel(
    const float* __restrict__ w, const float* __restrict__ s,
    float* __restrict__ out)
{
    const int i = blockIdx.x;
    const int jc = blockIdx.y;
    const int k = threadIdx.x;
    const float* wr = w + (size_t)i * N + jc * 80;
    const float* sp = s + (size_t)(jc * 80) * N + k;
    float a0 = 0.f, a1 = 0.f, a2 = 0.f, a3 = 0.f;
    for (int j = 0; j < 80; j += 4) {
        a0 += wr[j + 0] * sp[(size_t)(j + 0) * N];
        a1 += wr[j + 1] * sp[(size_t)(j + 1) * N];
        a2 += wr[j + 2] * sp[(size_t)(j + 2) * N];
        a3 += wr[j + 3] * sp[(size_t)(j + 3) * N];
    }
    atomicAdd(&out[(size_t)i * N + k], (a0 + a1) + (a2 + a3));
}

extern "C" void kernel_launch(void* const* d_in, const int* in_sizes, int n_in,
                              void* d_out, int out_size, void* d_ws, size_t ws_size,
                              hipStream_t stream)
{
    const float* s    = (const float*)d_in[0];
    const float* fut  = (const float*)d_in[1];
    const float* W    = (const float*)d_in[2];
    const float* bvec = (const float*)d_in[3];
    float* out = (float*)d_out;

    char* base = (char*)d_ws;
    float* wbuf   = (float*)base;                        // 409600 B
    float* colsum = (float*)(base + 409600);             // 1280 B
    uint4* spH = (uint4*)(base + 410880);                // 204800 B
    uint4* spL = (uint4*)(base + 615680);                // 204800 B
    uint4* wpH = (uint4*)(base + 820480);                // 204800 B
    uint4* wpL = (uint4*)(base + 1025280);               // 204800 B
    uint4* fpH = (uint4*)(base + 1230080);               // 65,536,000 B
    uint4* fpL = (uint4*)(base + 1230080 + 65536000);    // 65,536,000 B
    // total 132,302,080 B -- proven available (round-2 executed the packed path)

    prep_kernel<<<dim3(302), dim3(256), 0, stream>>>(
        s, W, wbuf, out, colsum, spH, spL, wpH, wpL);

    packf_kernel<<<dim3(1600), dim3(320), 0, stream>>>(fut, fpH, fpL);

    fused_kernel<<<dim3(3200), dim3(640), 0, stream>>>(
        fpH, fpL, spH, spL, wpH, wpL, bvec, colsum, wbuf);

    out_gemm_kernel<<<dim3(N, 4), dim3(320), 0, stream>>>(wbuf, s, out);
}

// Round 6
// 369.270 us; speedup vs baseline: 1.1624x; 1.1624x over previous
//
#include <hip/hip_runtime.h>
#include <hip/hip_bf16.h>
#include <math.h>

#define N 320
#define NN (N * N)          // 102400

typedef float f32x16 __attribute__((ext_vector_type(16)));
typedef short s16x8  __attribute__((ext_vector_type(8)));

#define MFMA32(a, b, c) __builtin_amdgcn_mfma_f32_32x32x16_bf16((a), (b), (c), 0, 0, 0)

union U4V { uint4 q; s16x8 v; };
union UAV { unsigned u[4]; s16x8 v; };

// truncation split: x = hi + lo with hi,lo bf16 (round-toward-zero; rel err ~2^-16 combined)
__device__ inline void split2(float x0, float x1, unsigned& hi, unsigned& lo) {
    unsigned u0 = __float_as_uint(x0), u1 = __float_as_uint(x1);
    hi = (u0 >> 16) | (u1 & 0xFFFF0000u);
    float d0 = x0 - __uint_as_float(u0 & 0xFFFF0000u);
    float d1 = x1 - __uint_as_float(u1 & 0xFFFF0000u);
    lo = (__float_as_uint(d0) >> 16) | (__float_as_uint(d1) & 0xFFFF0000u);
}

// ---------------- fused prep ----------------
// block roles:
//   [  0,100) zero wbuf
//   [100,200) zero out
//   [200,202) colsum[e] = sum_t s[t][e]
//   [202,252) pack s^T   (4 sub-blocks of 64 lanes per block)
//   [252,302) pack W^T
__global__ __launch_bounds__(256) void prep_kernel(
    const float* __restrict__ s, const float* __restrict__ W,
    float* __restrict__ wbuf, float* __restrict__ out, float* __restrict__ colsum,
    uint4* __restrict__ spH, uint4* __restrict__ spL,
    uint4* __restrict__ wpH, uint4* __restrict__ wpL)
{
    const int bid = blockIdx.x;
    const int tid = threadIdx.x;
    if (bid < 100) {
        ((float4*)wbuf)[bid * 256 + tid] = make_float4(0.f, 0.f, 0.f, 0.f);
    } else if (bid < 200) {
        ((float4*)out)[(bid - 100) * 256 + tid] = make_float4(0.f, 0.f, 0.f, 0.f);
    } else if (bid < 202) {
        int e = (bid - 200) * 256 + tid;
        if (e < N) {
            const float* sp = s + e;
            float a[8];
#pragma unroll
            for (int u = 0; u < 8; ++u) a[u] = 0.f;
            for (int t = 0; t < N; t += 8) {
#pragma unroll
                for (int u = 0; u < 8; ++u) a[u] += sp[(size_t)(t + u) * N];
            }
            colsum[e] = ((a[0] + a[1]) + (a[2] + a[3])) + ((a[4] + a[5]) + (a[6] + a[7]));
        }
    } else if (bid < 252) {
        int sub = (bid - 202) * 4 + (tid >> 6);     // 0..199 = et*20 + ts
        int l = tid & 63;
        int et = sub / 20, ts = sub % 20;
        int e = et * 32 + (l & 31);
        int t0 = ts * 16 + (l >> 5) * 8;
        unsigned hi[4], lo[4];
#pragma unroll
        for (int d = 0; d < 4; ++d)
            split2(s[(size_t)(t0 + 2 * d) * N + e], s[(size_t)(t0 + 2 * d + 1) * N + e],
                   hi[d], lo[d]);
        spH[sub * 64 + l] = make_uint4(hi[0], hi[1], hi[2], hi[3]);
        spL[sub * 64 + l] = make_uint4(lo[0], lo[1], lo[2], lo[3]);
    } else {
        int sub = (bid - 252) * 4 + (tid >> 6);     // 0..199 = jt*20 + ks
        int l = tid & 63;
        int jt = sub / 20, ks = sub % 20;
        int j = jt * 32 + (l & 31);
        int k0 = ks * 16 + (l >> 5) * 8;
        const float* wr = W + (size_t)j * N + k0;
        unsigned hi[4], lo[4];
#pragma unroll
        for (int d = 0; d < 4; ++d) split2(wr[2 * d], wr[2 * d + 1], hi[d], lo[d]);
        wpH[sub * 64 + l] = make_uint4(hi[0], hi[1], hi[2], hi[3]);
        wpL[sub * 64 + l] = make_uint4(lo[0], lo[1], lo[2], lo[3]);
    }
}

// ---------------- fused64: per (i, e-quarter 64) — F redundancy 5x, ONE B/softmax pass ---
// bid decode: x = bid&7 (XCD), g = bid>>3; iw = g/5, eq = g%5; i = iw*8 + x.
// The 5 eq-blocks of one i sit at consecutive per-XCD slots -> co-resident, F_i L2/L3-shared.
// Phase A: 6 MFMAs/iter into 2 chains (slabs 2eq, 2eq+1) sharing one F fragment.
// Phase B: ONE pass, 6 MFMAs/iter into 4 chains, W fragments amortized across both slabs.
// LDS (dynamic, 81920 B = exactly 2 blocks/CU):
//   phase A->B: G[4 planes][10240 u16]  (slab0 hi, slab0 lo, slab1 hi, slab1 lo)
//   epilogue:   S[64 rows][320 f32] overlays G; row max/inv written into own row's slots 0,1.
__global__ __launch_bounds__(640, 4) void fused64_kernel(
    const float* __restrict__ fut,
    const uint4* __restrict__ spH, const uint4* __restrict__ spL,
    const uint4* __restrict__ wpH, const uint4* __restrict__ wpL,
    const float* __restrict__ bvec, const float* __restrict__ colsum,
    float* __restrict__ w)
{
    extern __shared__ char smraw[];
    unsigned short* Gsh = (unsigned short*)smraw;
    float* Ssh = (float*)smraw;

    const int bid = blockIdx.x;
    const int x  = bid & 7;
    const int g  = bid >> 3;
    const int iw = g / 5, eq = g % 5;
    const int i  = iw * 8 + x;
    const int tid = threadIdx.x;
    const int wid = tid >> 6;         // wave 0..9 = 32-wide j column tile
    const int lane = tid & 63;
    const int l31 = lane & 31;
    const int hf  = lane >> 5;

    // ---------------- phase A: G[2 slabs] = s^T @ F_i ----------------
    f32x16 acc0, acc1;
#pragma unroll
    for (int r = 0; r < 16; ++r) { acc0[r] = 0.f; acc1[r] = 0.f; }

    const float* fbase = fut + (size_t)i * NN + (size_t)(hf * 8) * N + wid * 32 + l31;
    const uint4* aH0 = spH + (size_t)((eq * 2 + 0) * 20) * 64 + lane;
    const uint4* aL0 = spL + (size_t)((eq * 2 + 0) * 20) * 64 + lane;
    const uint4* aH1 = spH + (size_t)((eq * 2 + 1) * 20) * 64 + lane;
    const uint4* aL1 = spL + (size_t)((eq * 2 + 1) * 20) * 64 + lane;

#pragma unroll 2
    for (int ts = 0; ts < 20; ++ts) {
        const float* fp = fbase + (size_t)(ts * 16) * N;
        float f[8];
#pragma unroll
        for (int m = 0; m < 8; ++m) f[m] = fp[(size_t)m * N];
        UAV bh, bl;
#pragma unroll
        for (int d = 0; d < 4; ++d) split2(f[2 * d], f[2 * d + 1], bh.u[d], bl.u[d]);
        U4V a0h, a0l, a1h, a1l;
        a0h.q = aH0[ts * 64]; a0l.q = aL0[ts * 64];
        a1h.q = aH1[ts * 64]; a1l.q = aL1[ts * 64];
        acc0 = MFMA32(a0h.v, bh.v, acc0);
        acc1 = MFMA32(a1h.v, bh.v, acc1);
        acc0 = MFMA32(a0l.v, bh.v, acc0);
        acc1 = MFMA32(a1l.v, bh.v, acc1);
        acc0 = MFMA32(a0h.v, bl.v, acc0);
        acc1 = MFMA32(a1h.v, bl.v, acc1);
    }

    // G -> LDS bf16 hi/lo in frag-linear swizzled layout (both slabs)
    {
        unsigned short* GH0 = Gsh;
        unsigned short* GL0 = Gsh + 10240;
        unsigned short* GH1 = Gsh + 20480;
        unsigned short* GL1 = Gsh + 30720;
        const int c  = wid * 4 + (l31 >> 3);
        const int jj = l31 & 7;
        const int sw = c & 7;
#pragma unroll
        for (int r = 0; r < 16; ++r) {
            int e = (r & 3) + ((r >> 2) << 3) + (hf << 2);
            int off = (c * 32 + (e ^ sw)) * 8 + jj;
            {
                float xv = acc0[r];
                unsigned u = __float_as_uint(xv);
                float d = xv - __uint_as_float(u & 0xFFFF0000u);
                GH0[off] = (unsigned short)(u >> 16);
                GL0[off] = (unsigned short)(__float_as_uint(d) >> 16);
            }
            {
                float xv = acc1[r];
                unsigned u = __float_as_uint(xv);
                float d = xv - __uint_as_float(u & 0xFFFF0000u);
                GH1[off] = (unsigned short)(u >> 16);
                GL1[off] = (unsigned short)(__float_as_uint(d) >> 16);
            }
        }
    }
    __syncthreads();   // B1: G visible

    // ---------------- phase B: S = G @ W^T (+ colsum*b), both slabs, one pass -------
    f32x16 p0a, p0b, p1a, p1b;
#pragma unroll
    for (int r = 0; r < 16; ++r) { p0a[r] = 0.f; p0b[r] = 0.f; p1a[r] = 0.f; p1b[r] = 0.f; }

    const uint4* bHp = wpH + (size_t)(wid * 20) * 64 + lane;
    const uint4* bLp = wpL + (size_t)(wid * 20) * 64 + lane;
    const unsigned short* GH0 = Gsh;
    const unsigned short* GL0 = Gsh + 10240;
    const unsigned short* GH1 = Gsh + 20480;
    const unsigned short* GL1 = Gsh + 30720;

#pragma unroll 2
    for (int ks = 0; ks < 20; ++ks) {
        int c = ks * 2 + hf;
        int off = (c * 32 + (l31 ^ (c & 7))) * 8;
        s16x8 gh0 = *(const s16x8*)&GH0[off];
        s16x8 gl0 = *(const s16x8*)&GL0[off];
        s16x8 gh1 = *(const s16x8*)&GH1[off];
        s16x8 gl1 = *(const s16x8*)&GL1[off];
        U4V wh, wl;
        wh.q = bHp[ks * 64];
        wl.q = bLp[ks * 64];
        p0a = MFMA32(gh0, wh.v, p0a);
        p1a = MFMA32(gh1, wh.v, p1a);
        p0b = MFMA32(gl0, wh.v, p0b);
        p1b = MFMA32(gl1, wh.v, p1b);
        p0b = MFMA32(gh0, wl.v, p0b);
        p1b = MFMA32(gh1, wl.v, p1b);
    }

    const int jcol = wid * 32 + l31;
    const float bj = bvec[jcol];
    float v0[16], v1[16];
#pragma unroll
    for (int r = 0; r < 16; ++r) {
        int e = (r & 3) + ((r >> 2) << 3) + (hf << 2);
        v0[r] = (p0a[r] + p0b[r]) + colsum[eq * 64 + e] * bj;
        v1[r] = (p1a[r] + p1b[r]) + colsum[eq * 64 + 32 + e] * bj;
    }
    __syncthreads();   // B2: all G reads done before S overlays G

#pragma unroll
    for (int r = 0; r < 16; ++r) {
        int e = (r & 3) + ((r >> 2) << 3) + (hf << 2);
        Ssh[e * 320 + jcol] = v0[r];
        Ssh[(32 + e) * 320 + jcol] = v1[r];
    }
    __syncthreads();   // B3

    // row sweeps: half-wave hw (0..19) handles rows q*20+hw (<64).
    // Row max and 1/sum are written into the row's OWN slots 0,1 (read-before-write safe,
    // no other half-wave touches this row).
    const int hw = tid >> 5;
    const int li = tid & 31;
#pragma unroll
    for (int q = 0; q < 4; ++q) {
        int row = q * 20 + hw;
        if (row < 64) {
            float xr[10];
            float m = -3.4e38f;
#pragma unroll
            for (int k = 0; k < 10; ++k) {
                xr[k] = Ssh[row * 320 + li + 32 * k];
                m = fmaxf(m, xr[k]);
            }
#pragma unroll
            for (int off = 16; off; off >>= 1) m = fmaxf(m, __shfl_xor(m, off, 64));
            float ss = 0.f;
#pragma unroll
            for (int k = 0; k < 10; ++k) ss += __expf(xr[k] - m);
#pragma unroll
            for (int off = 16; off; off >>= 1) ss += __shfl_xor(ss, off, 64);
            if (li == 0) { Ssh[row * 320 + 0] = m; Ssh[row * 320 + 1] = 1.0f / ss; }
        }
    }
    __syncthreads();   // B4

    float wcol = 0.f;
#pragma unroll
    for (int r = 0; r < 16; ++r) {
        int e = (r & 3) + ((r >> 2) << 3) + (hf << 2);
        wcol += __expf(v0[r] - Ssh[e * 320]) * Ssh[e * 320 + 1];             // broadcast reads
        wcol += __expf(v1[r] - Ssh[(32 + e) * 320]) * Ssh[(32 + e) * 320 + 1];
    }
    wcol += __shfl_xor(wcol, 32, 64);
    if (hf == 0) atomicAdd(&w[(size_t)i * N + jcol], wcol);
}

// ---------------- out[i][k] += sum_{j in chunk} w[i][j] * s[j][k] ----------------
__global__ __launch_bounds__(320) void out_gemm_kernel(
    const float* __restrict__ w, const float* __restrict__ s,
    float* __restrict__ out)
{
    const int i = blockIdx.x;
    const int jc = blockIdx.y;
    const int k = threadIdx.x;
    const float* wr = w + (size_t)i * N + jc * 80;
    const float* sp = s + (size_t)(jc * 80) * N + k;
    float a0 = 0.f, a1 = 0.f, a2 = 0.f, a3 = 0.f;
    for (int j = 0; j < 80; j += 4) {
        a0 += wr[j + 0] * sp[(size_t)(j + 0) * N];
        a1 += wr[j + 1] * sp[(size_t)(j + 1) * N];
        a2 += wr[j + 2] * sp[(size_t)(j + 2) * N];
        a3 += wr[j + 3] * sp[(size_t)(j + 3) * N];
    }
    atomicAdd(&out[(size_t)i * N + k], (a0 + a1) + (a2 + a3));
}

extern "C" void kernel_launch(void* const* d_in, const int* in_sizes, int n_in,
                              void* d_out, int out_size, void* d_ws, size_t ws_size,
                              hipStream_t stream)
{
    const float* s    = (const float*)d_in[0];
    const float* fut  = (const float*)d_in[1];
    const float* W    = (const float*)d_in[2];
    const float* bvec = (const float*)d_in[3];
    float* out = (float*)d_out;

    char* base = (char*)d_ws;
    float* wbuf   = (float*)base;                        // 409600 B
    float* colsum = (float*)(base + 409600);             // 1280 B
    uint4* spH = (uint4*)(base + 410880);                // 204800 B
    uint4* spL = (uint4*)(base + 615680);                // 204800 B
    uint4* wpH = (uint4*)(base + 820480);                // 204800 B
    uint4* wpL = (uint4*)(base + 1025280);               // 204800 B

    static bool attr_done = false;
    if (!attr_done) {
        (void)hipFuncSetAttribute((const void*)fused64_kernel,
                                  hipFuncAttributeMaxDynamicSharedMemorySize, 81920);
        attr_done = true;
    }

    prep_kernel<<<dim3(302), dim3(256), 0, stream>>>(
        s, W, wbuf, out, colsum, spH, spL, wpH, wpL);

    fused64_kernel<<<dim3(1600), dim3(640), 81920, stream>>>(
        fut, spH, spL, wpH, wpL, bvec, colsum, wbuf);

    out_gemm_kernel<<<dim3(N, 4), dim3(320), 0, stream>>>(wbuf, s, out);
}